// Round 10
// baseline (44.258 us; speedup 1.0000x reference)
//
#include <hip/hip_runtime.h>

// YOLO loss: S=1024, 30 f32 channels/cell, channel-last contiguous.
// loss = 5*xy + 5*box + (conf_t-conf_p)^2 + cls_masked
//
// R1: coalesced LDS staging fixed 3.25x over-fetch (236 -> 46.8us).
// R2: occupancy 19->42% flat -> convoy/latency, not occupancy.
// R4/R7/R8: array/lambda prefetch -> SROA failure -> scratch (217MB writes).
// R9: named-scalar staging promoted (WRITE 16KB), 2-deep pipeline: 42.9us.
//     Residual stall: STORE waits on loads issued only ~1 compute-phase ago.
// R10: 3-deep rotation. 64-cell tiles (15,360B/buf) x3 = 46KB LDS -> 3
//     blocks/CU (12 waves). STORE(k+1) consumes loads issued a FULL
//     iteration earlier; LOAD(k+2) issues every iteration -> no bubble.
//     Quarter-cell/thread compute; named scalars only (no arrays/lambdas).

constexpr int CH         = 30;
constexpr int NCELL      = 1024 * 1024;
constexpr int BLOCK      = 256;
constexpr int TILE_CELLS = 64;
constexpr int TPF        = TILE_CELLS * CH;       // 1920 floats per tensor
constexpr int BUFFLOATS  = 2 * TPF;               // 3840 combined [pred|tgt]
constexpr int NTILES     = NCELL / TILE_CELLS;    // 16384
constexpr int GRID       = 768;                   // 3 blocks/CU resident

__device__ __forceinline__ float wave_reduce_sum(float v) {
#pragma unroll
    for (int off = 32; off > 0; off >>= 1)
        v += __shfl_down(v, off, 64);
    return v;
}

__global__ __launch_bounds__(BLOCK, 3) void yolo_partial_kernel(
        const float* __restrict__ pred,
        const float* __restrict__ tgt,
        float* __restrict__ partial) {
    // 3 rotating buffers, each = combined tile [pred 0..1919 | tgt 1920..3839]
    __shared__ float4 sbuf4[3 * BUFFLOATS / 4];   // 46,080 B

    const int tid  = threadIdx.x;
    const int wv   = tid >> 6;
    const int ln   = tid & 63;
    const int cell = tid >> 2;        // 0..63
    const int q    = tid & 3;         // quarter: q<2 also does box q

    // Named staging registers: 15 floats = 3xfloat4 + float2 + float.
    // Combined-tile float index per thread: c0@4*tid, c1@1024+4*tid,
    // c2@2048+4*tid, c3@3072+2*tid, c4@3584+tid. Boundary pred/tgt at 1920:
    // only c1 crosses (at tid==224), handled by per-lane pointer select.
    float4 c0, c1, c2;
    float2 c3;
    float  c4;

#define LOAD_TILE(tile)                                                       \
    do {                                                                      \
        const size_t tb = (size_t)(tile) * TPF;                               \
        const float* pb = pred + tb;                                          \
        const float* gb = tgt + tb;                                           \
        c0 = *reinterpret_cast<const float4*>(pb + 4 * tid);                  \
        const float* s1 = (tid < 224) ? (pb + 1024 + 4 * tid)                 \
                                      : (gb + (4 * tid - 896));               \
        c1 = *reinterpret_cast<const float4*>(s1);                            \
        c2 = *reinterpret_cast<const float4*>(gb + 128 + 4 * tid);            \
        c3 = *reinterpret_cast<const float2*>(gb + 1152 + 2 * tid);           \
        c4 = gb[1664 + tid];                                                  \
    } while (0)

#define STORE_TILE(b)                                                         \
    do {                                                                      \
        float* sf = reinterpret_cast<float*>(&sbuf4[0]) + (b) * BUFFLOATS;    \
        float4* s4 = reinterpret_cast<float4*>(sf);                           \
        s4[0 * 256 + tid] = c0;                                               \
        s4[1 * 256 + tid] = c1;                                               \
        s4[2 * 256 + tid] = c2;                                               \
        reinterpret_cast<float2*>(sf)[1536 + tid] = c3;                       \
        sf[3584 + tid] = c4;                                                  \
    } while (0)

    int t  = blockIdx.x;
    int it = 0;

    LOAD_TILE(t);                 // tile 0 -> regs -> buf0
    STORE_TILE(0);
    if (t + GRID < NTILES) LOAD_TILE(t + GRID);   // 1-ahead in flight
    __syncthreads();

    float acc = 0.0f;
    for (;;) {
        // invariant: buf[it%3] holds tile t; regs hold tile t+GRID (if any)
        const int b_cur = it % 3;
        if (t + GRID < NTILES)     STORE_TILE((it + 1) % 3);  // loads landed
        if (t + 2 * GRID < NTILES) LOAD_TILE(t + 2 * GRID);   // issue 2-ahead
        __builtin_amdgcn_sched_barrier(0);                     // pin above compute

        const float* bf = reinterpret_cast<const float*>(&sbuf4[0]) + b_cur * BUFFLOATS;
        const float* pp = bf + cell * CH;
        const float* tt = bf + TPF + cell * CH;

        // box (lanes q<2 only): channels [5q..5q+4] = (conf,x,y,w,h)
        if (q < 2) {
            const int o = 5 * q;
            const float conf_p = pp[o + 0];
            const float x_p    = pp[o + 1];
            const float y_p    = pp[o + 2];
            const float w_p    = sqrtf(fabsf(pp[o + 3]));
            const float h_p    = sqrtf(fabsf(pp[o + 4]));
            const float conf_t = tt[o + 0];
            const float x_t    = tt[o + 1];
            const float y_t    = tt[o + 2];
            const float w_t    = sqrtf(tt[o + 3]);
            const float h_t    = sqrtf(tt[o + 4]);

            const float dx = x_t - x_p, dy = y_t - y_p;
            const float dw = w_t - w_p, dh = h_t - h_p;
            const float dc = conf_t - conf_p;

            acc += 5.0f * ((dx * dx + dy * dy) * conf_t)
                 + 5.0f * ((dw * dw + dh * dh) * conf_t)
                 + dc * dc;
        }

        // class: 5 channels per lane [10+5q .. 10+5q+4]; the mask needs the
        // FULL 20-channel target sum -> combine across the 4-lane group.
        {
            float ssum = 0.0f, per_cell = 0.0f;
            const int co = 10 + 5 * q;
#pragma unroll
            for (int k = 0; k < 5; ++k) {
                const float tc = tt[co + k];
                const float pc = pp[co + k];
                ssum     += tc;
                per_cell += tc * tc - pc * pc;
            }
            float tot = ssum;
            tot += __shfl_xor(tot, 1, 64);
            tot += __shfl_xor(tot, 2, 64);
            acc += (tot == 1.0f) ? per_cell : 0.0f;  // 4 lanes sum to full term
        }

        __syncthreads();
        t += GRID;
        ++it;
        if (t >= NTILES) break;
    }

    // block reduction: wave shuffle -> LDS across 4 waves
    __shared__ float red[BLOCK / 64];
    float v = wave_reduce_sum(acc);
    if (ln == 0) red[wv] = v;
    __syncthreads();
    if (wv == 0) {
        v = (ln < (BLOCK / 64)) ? red[ln] : 0.0f;
        v = wave_reduce_sum(v);
        if (ln == 0) partial[blockIdx.x] = v;
    }
#undef LOAD_TILE
#undef STORE_TILE
}

__global__ __launch_bounds__(256) void yolo_final_kernel(
        const float* __restrict__ partial,
        float* __restrict__ out,
        int n) {
    float acc = 0.0f;
    for (int i = threadIdx.x; i < n; i += 256)
        acc += partial[i];

    __shared__ float red[4];
    const int lane = threadIdx.x & 63;
    const int wid  = threadIdx.x >> 6;
    float v = wave_reduce_sum(acc);
    if (lane == 0) red[wid] = v;
    __syncthreads();
    if (wid == 0) {
        v = (lane < 4) ? red[lane] : 0.0f;
        v = wave_reduce_sum(v);
        if (lane == 0) out[0] = v;
    }
}

extern "C" void kernel_launch(void* const* d_in, const int* in_sizes, int n_in,
                              void* d_out, int out_size, void* d_ws, size_t ws_size,
                              hipStream_t stream) {
    const float* pred = (const float*)d_in[0];
    const float* tgt  = (const float*)d_in[1];
    float* out        = (float*)d_out;
    float* partial    = (float*)d_ws;   // GRID floats = 3 KB

    yolo_partial_kernel<<<GRID, BLOCK, 0, stream>>>(pred, tgt, partial);
    yolo_final_kernel<<<1, 256, 0, stream>>>(partial, out, GRID);
}

// Round 11
// 43.938 us; speedup vs baseline: 1.0073x; 1.0073x over previous
//
#include <hip/hip_runtime.h>

// YOLO loss: S=1024, 30 f32 channels/cell, channel-last contiguous.
// loss = 5*xy + 5*box + (conf_t-conf_p)^2 + cls_masked
//
// FINAL (= R9, best measured: 42.9us = 5.9 TB/s blended, 93% of the 6.3 TB/s
// measured stream ceiling; FETCH at the 123MB ideal, no spill, no conflicts).
//
// Journal:
// R1: coalesced LDS staging fixed 3.25x over-fetch (236 -> 46.8us).
// R2: occupancy 19->42% flat -> convoy/latency, not occupancy.
// R4/R7/R8: array/lambda prefetch -> SROA failure -> scratch (217MB writes).
//   Lesson: staging regs must be straight-line NAMED scalars.
// R5/R6: global_load_lds variants NaN'd twice -> dropped.
// R9: named-scalar 2-deep pipeline: 42.9us.
// R10: 3-deep rotation + 29% occupancy: 44.3us (worse) -> memory-side wall.
//   Four schedules (depth 0/0/1/2, occ 19-42%) all 43-47us => roofline.

constexpr int CH         = 30;
constexpr int NCELL      = 1024 * 1024;
constexpr int BLOCK      = 256;
constexpr int TILE_CELLS = 128;
constexpr int TPF        = TILE_CELLS * CH;       // 3840 floats per tensor
constexpr int GRID       = 512;                   // 2 blocks/CU resident
constexpr int NTILES     = NCELL / TILE_CELLS;    // 8192
constexpr int NIT        = NTILES / GRID;         // 16 tiles per block

__device__ __forceinline__ float wave_reduce_sum(float v) {
#pragma unroll
    for (int off = 32; off > 0; off >>= 1)
        v += __shfl_down(v, off, 64);
    return v;
}

__global__ __launch_bounds__(BLOCK, 2) void yolo_partial_kernel(
        const float* __restrict__ pred,
        const float* __restrict__ tgt,
        float* __restrict__ partial) {
    // [buf][pred floats 0..3839 | tgt floats 3840..7679] : 61,440 B total
    __shared__ float4 sbuf4[2][2 * TPF / 4];

    const int tid  = threadIdx.x;
    const int wv   = tid >> 6;
    const int ln   = tid & 63;
    const int cell = tid >> 1;        // 0..127
    const int half = tid & 1;         // which box / class half

    // Named staging registers: 3 float4 + 1 float2 + 1 float per tensor.
    float4 p0, p1, p2, t0, t1, t2;
    float2 p3, t3;
    float  p4, t4;

#define LOAD_TILE(tile)                                                      \
    do {                                                                     \
        const size_t tb = (size_t)(tile) * TPF;                              \
        const float4* pf4 = reinterpret_cast<const float4*>(pred + tb);      \
        const float4* tf4 = reinterpret_cast<const float4*>(tgt  + tb);      \
        const float2* pf2 = reinterpret_cast<const float2*>(pred + tb);      \
        const float2* tf2 = reinterpret_cast<const float2*>(tgt  + tb);      \
        p0 = pf4[0 * 256 + tid];  t0 = tf4[0 * 256 + tid];                   \
        p1 = pf4[1 * 256 + tid];  t1 = tf4[1 * 256 + tid];                   \
        p2 = pf4[2 * 256 + tid];  t2 = tf4[2 * 256 + tid];                   \
        p3 = pf2[1536 + tid];     t3 = tf2[1536 + tid];                      \
        p4 = pred[tb + 3584 + tid]; t4 = tgt[tb + 3584 + tid];               \
    } while (0)

#define STORE_TILE(b)                                                        \
    do {                                                                     \
        float*  sf  = reinterpret_cast<float*>(&sbuf4[(b)][0]);              \
        float4* sp4 = reinterpret_cast<float4*>(sf);                         \
        float4* st4 = reinterpret_cast<float4*>(sf + TPF);                   \
        float2* sp2 = reinterpret_cast<float2*>(sf);                         \
        float2* st2 = reinterpret_cast<float2*>(sf + TPF);                   \
        sp4[0 * 256 + tid] = p0;  st4[0 * 256 + tid] = t0;                   \
        sp4[1 * 256 + tid] = p1;  st4[1 * 256 + tid] = t1;                   \
        sp4[2 * 256 + tid] = p2;  st4[2 * 256 + tid] = t2;                   \
        sp2[1536 + tid] = p3;     st2[1536 + tid] = t3;                      \
        sf[3584 + tid] = p4;      sf[TPF + 3584 + tid] = t4;                 \
    } while (0)

    int t = blockIdx.x;
    LOAD_TILE(t);              // prologue: tile 0 -> regs -> buf0
    STORE_TILE(0);
    __syncthreads();

    float acc = 0.0f;
    for (int it = 0; it < NIT; ++it) {
        const int cur = it & 1;
        const bool havenext = (it + 1 < NIT);

        if (havenext) LOAD_TILE(t + GRID);   // in flight during compute below
        __builtin_amdgcn_sched_barrier(0);    // pin loads above compute

        const float* bf = reinterpret_cast<const float*>(&sbuf4[cur][0]);
        const float* pp = bf + cell * CH;
        const float* tt = bf + TPF + cell * CH;

        // this thread's box: channels [5*half .. 5*half+4] = (conf,x,y,w,h)
        {
            const int o = 5 * half;
            const float conf_p = pp[o + 0];
            const float x_p    = pp[o + 1];
            const float y_p    = pp[o + 2];
            const float w_p    = sqrtf(fabsf(pp[o + 3]));
            const float h_p    = sqrtf(fabsf(pp[o + 4]));
            const float conf_t = tt[o + 0];
            const float x_t    = tt[o + 1];
            const float y_t    = tt[o + 2];
            const float w_t    = sqrtf(tt[o + 3]);
            const float h_t    = sqrtf(tt[o + 4]);

            const float dx = x_t - x_p, dy = y_t - y_p;
            const float dw = w_t - w_p, dh = h_t - h_p;
            const float dc = conf_t - conf_p;

            acc += 5.0f * ((dx * dx + dy * dy) * conf_t)
                 + 5.0f * ((dw * dw + dh * dh) * conf_t)
                 + dc * dc;
        }

        // this thread's class half: channels [10+10*half ..+9]; the mask
        // needs the FULL 20-channel target sum -> combine across lane pair.
        {
            float ssum = 0.0f, per_cell = 0.0f;
            const int co = 10 + 10 * half;
#pragma unroll
            for (int k = 0; k < 10; ++k) {
                const float tc = tt[co + k];
                const float pc = pp[co + k];
                ssum     += tc;
                per_cell += tc * tc - pc * pc;
            }
            const float tot = ssum + __shfl_xor(ssum, 1, 64);
            acc += (tot == 1.0f) ? per_cell : 0.0f;
        }

        // stage tile t+GRID into the other buffer (its readers finished
        // before the previous barrier).
        if (havenext) STORE_TILE(cur ^ 1);
        __syncthreads();
        t += GRID;
    }

    // block reduction: wave shuffle -> LDS across 4 waves
    __shared__ float red[BLOCK / 64];
    float v = wave_reduce_sum(acc);
    if (ln == 0) red[wv] = v;
    __syncthreads();
    if (wv == 0) {
        v = (ln < (BLOCK / 64)) ? red[ln] : 0.0f;
        v = wave_reduce_sum(v);
        if (ln == 0) partial[blockIdx.x] = v;
    }
#undef LOAD_TILE
#undef STORE_TILE
}

__global__ __launch_bounds__(256) void yolo_final_kernel(
        const float* __restrict__ partial,
        float* __restrict__ out,
        int n) {
    float acc = 0.0f;
    for (int i = threadIdx.x; i < n; i += 256)
        acc += partial[i];

    __shared__ float red[4];
    const int lane = threadIdx.x & 63;
    const int wid  = threadIdx.x >> 6;
    float v = wave_reduce_sum(acc);
    if (lane == 0) red[wid] = v;
    __syncthreads();
    if (wid == 0) {
        v = (lane < 4) ? red[lane] : 0.0f;
        v = wave_reduce_sum(v);
        if (lane == 0) out[0] = v;
    }
}

extern "C" void kernel_launch(void* const* d_in, const int* in_sizes, int n_in,
                              void* d_out, int out_size, void* d_ws, size_t ws_size,
                              hipStream_t stream) {
    const float* pred = (const float*)d_in[0];
    const float* tgt  = (const float*)d_in[1];
    float* out        = (float*)d_out;
    float* partial    = (float*)d_ws;   // GRID floats = 2 KB

    yolo_partial_kernel<<<GRID, BLOCK, 0, stream>>>(pred, tgt, partial);
    yolo_final_kernel<<<1, 256, 0, stream>>>(partial, out, GRID);
}